// Round 5
// baseline (876.862 us; speedup 1.0000x reference)
//
#include <hip/hip_runtime.h>
#include <hip/hip_bf16.h>

// Problem constants (B=1)
#define CL 2048   // sequence length
#define CD 1024   // hidden
#define CH 16     // heads
#define CHD 64    // head dim
#define NEGS -1e30f

typedef __attribute__((ext_vector_type(8))) short short8;  // 8 x bf16 frag
typedef __attribute__((ext_vector_type(4))) float f32x4;
// Scores live in one of these per row: first-class SSA vector -> NEVER alloca'd
// (round 3/4 post-mortem: float s[4][32] arrays stayed in scratch, VGPR=52,
//  530 MB/dispatch of spill writes. Vectors fix the SROA-before-unroll trap.)
typedef __attribute__((ext_vector_type(32))) float f32x32;

__device__ __forceinline__ float wave_sum(float x) {
#pragma unroll
  for (int m = 32; m >= 1; m >>= 1) x += __shfl_xor(x, m, 64);
  return x;  // all 64 lanes hold the total
}

// Broadcast lane `l` of v to all lanes (VALU v_readlane, not the LDS pipe).
__device__ __forceinline__ float rl_f(float v, int l) {
  return __int_as_float(__builtin_amdgcn_readlane(__float_as_int(v), l));
}

// fp32 -> (hi, lo) bf16 planes: x ~= hi + lo to ~16 mantissa bits.
__global__ __launch_bounds__(256) void split_bf16(
    const float* __restrict__ x, short* __restrict__ hi, short* __restrict__ lo,
    int n4) {
  const int i = blockIdx.x * 256 + threadIdx.x;
  if (i >= n4) return;
  const float4 v = reinterpret_cast<const float4*>(x)[i];
  const float vv[4] = {v.x, v.y, v.z, v.w};
  short hh[4], ll[4];
#pragma unroll
  for (int e = 0; e < 4; e++) {
    __hip_bfloat16 bh = __float2bfloat16(vv[e]);
    float r = vv[e] - __bfloat162float(bh);
    __hip_bfloat16 bl = __float2bfloat16(r);
    hh[e] = __builtin_bit_cast(short, bh);
    ll[e] = __builtin_bit_cast(short, bl);
  }
  reinterpret_cast<short4*>(hi)[i] = make_short4(hh[0], hh[1], hh[2], hh[3]);
  reinterpret_cast<short4*>(lo)[i] = make_short4(ll[0], ll[1], ll[2], ll[3]);
}

// C[2048,1024] = (Ah+Al) * (B?h+B?l)^T via 3-term split-bf16 MFMA, fp32 out.
// 128x128 tile/WG, LDS-staged BK=32, 4 waves (2x2), wave tile 64x64.
__global__ __launch_bounds__(256, 2) void gemm128_split(
    const short* __restrict__ Ah, const short* __restrict__ Al,
    const short* __restrict__ B0h, const short* __restrict__ B0l,
    const short* __restrict__ B1h, const short* __restrict__ B1l,
    const short* __restrict__ B2h, const short* __restrict__ B2l,
    float* __restrict__ C0, float* __restrict__ C1, float* __restrict__ C2) {
  __shared__ short AhS[128][32], AlS[128][32], BhS[128][32], BlS[128][32];
  const int tid = threadIdx.x, lane = tid & 63, wave = tid >> 6;
  const int l15 = lane & 15, quad = lane >> 4;
  const int sel = blockIdx.x >> 3, nb = blockIdx.x & 7;
  const short* Bh = sel == 0 ? B0h : (sel == 1 ? B1h : B2h);
  const short* Bl = sel == 0 ? B0l : (sel == 1 ? B1l : B2l);
  float* C = sel == 0 ? C0 : (sel == 1 ? C1 : C2);
  const int m0 = blockIdx.y * 128, n0 = nb * 128;
  const int wm = (wave >> 1) * 64, wn = (wave & 1) * 64;

  f32x4 acc[4][4];
#pragma unroll
  for (int i = 0; i < 4; i++)
#pragma unroll
    for (int j = 0; j < 4; j++) acc[i][j] = {0.f, 0.f, 0.f, 0.f};

  // Staging: wave p owns plane p (Ah/Al/Bh/Bl), 8 KB each per k-step.
  const short* gsrc = wave == 0 ? Ah : wave == 1 ? Al : wave == 2 ? Bh : Bl;
  short(*ldst)[32] = wave == 0 ? AhS : wave == 1 ? AlS : wave == 2 ? BhS : BlS;
  const int srow0 = (wave < 2) ? m0 : n0;

  for (int k0 = 0; k0 < CD; k0 += 32) {
#pragma unroll
    for (int i = 0; i < 8; i++) {
      const int ci = i * 64 + lane;        // 0..511 16B-chunks
      const int r = ci >> 2, kc = (ci & 3) * 8;
      *reinterpret_cast<short8*>(&ldst[r][kc]) =
          *reinterpret_cast<const short8*>(&gsrc[(size_t)(srow0 + r) * CD + k0 + kc]);
    }
    __syncthreads();
    short8 a_h[4], a_l[4], b_h[4], b_l[4];
#pragma unroll
    for (int i = 0; i < 4; i++) {
      a_h[i] = *reinterpret_cast<const short8*>(&AhS[wm + i * 16 + l15][quad * 8]);
      a_l[i] = *reinterpret_cast<const short8*>(&AlS[wm + i * 16 + l15][quad * 8]);
      b_h[i] = *reinterpret_cast<const short8*>(&BhS[wn + i * 16 + l15][quad * 8]);
      b_l[i] = *reinterpret_cast<const short8*>(&BlS[wn + i * 16 + l15][quad * 8]);
    }
#pragma unroll
    for (int im = 0; im < 4; im++)
#pragma unroll
      for (int in = 0; in < 4; in++) {  // same term order as round 3/4 (numerics)
        acc[im][in] = __builtin_amdgcn_mfma_f32_16x16x32_bf16(a_h[im], b_l[in], acc[im][in], 0, 0, 0);
        acc[im][in] = __builtin_amdgcn_mfma_f32_16x16x32_bf16(a_l[im], b_h[in], acc[im][in], 0, 0, 0);
        acc[im][in] = __builtin_amdgcn_mfma_f32_16x16x32_bf16(a_h[im], b_h[in], acc[im][in], 0, 0, 0);
      }
    __syncthreads();
  }

#pragma unroll
  for (int im = 0; im < 4; im++)
#pragma unroll
    for (int in = 0; in < 4; in++)
#pragma unroll
      for (int r = 0; r < 4; r++)
        C[(size_t)(m0 + wm + im * 16 + quad * 4 + r) * CD + n0 + wn + in * 16 + l15] =
            acc[im][in][r];
}

// Per-row entmax on register scores s[0..31] (col = 64t + lane), NEGS = invalid.
// s is an SSA vector value; all indices below are compile-time constants.
// Bit-identical arithmetic order to the round-2/3/4 passing versions.
__device__ __forceinline__ float entmax_row(f32x32& s, int n) {
  float ssum = 0.f;
#pragma unroll
  for (int t = 0; t < 32; t++) {
    const float sv = s[t];
    if (sv > -1e29f) ssum += sv;
  }
  ssum = wave_sum(ssum);

  float tau = (ssum - 1.f) / (float)n;
  int cnt = n;
  for (int it = 0; it < 1024; it++) {
    float cs = 0.f, cn = 0.f;
#pragma unroll
    for (int t = 0; t < 32; t++) {
      const float sv = s[t];
      if (sv > tau) { cs += sv; cn += 1.f; }  // NEGS never > tau
    }
    cs = wave_sum(cs);
    cn = wave_sum(cn);
    const int newcnt = (int)cn;
    tau = (cs - 1.f) / cn;
    if (newcnt == cnt) break;
    cnt = newcnt;
  }

  // Reference quirk: tau_star uses the FULL masked row sum, not the top-k sum.
  const float tau_star = (ssum - 1.f) / (float)cnt;
  float psum = 0.f;
#pragma unroll
  for (int t = 0; t < 32; t++) {
    float p = s[t] - tau_star;
    p = p > 0.f ? p : 0.f;
    s[t] = p;
    psum += p;
  }
  psum = wave_sum(psum);
  return 1.f / (psum + 1e-10f);
}

// WG = 256 thr (4 waves) x (head h, 16 query rows); wave w owns rows q0+4w..+3.
// Scores: four named f32x32 vectors (128 VGPRs) -> guaranteed register-resident.
// Tile loops are dynamic (jt < ntiles): vector element access via insert/extract.
__global__ __launch_bounds__(256, 1) void attn_entmax5(
    const float* __restrict__ q, const float* __restrict__ k,
    const float* __restrict__ v, short* __restrict__ oh, short* __restrict__ ol) {
  __shared__ float KT[64][68];  // 17.4 KB; b128 reads conflict-free

  const int tid = threadIdx.x, lane = tid & 63, wave = tid >> 6;
  const int h = blockIdx.y, q0 = blockIdx.x * 16;
  const int col0 = h * CHD;
  const int r0 = q0 + wave * 4;                 // rows r0..r0+3
  const int ntiles = (q0 + 79) >> 6;            // cols 0..q0+15 (WG-uniform)

  const float qr0 = q[(size_t)(r0 + 0) * CD + col0 + lane];
  const float qr1 = q[(size_t)(r0 + 1) * CD + col0 + lane];
  const float qr2 = q[(size_t)(r0 + 2) * CD + col0 + lane];
  const float qr3 = q[(size_t)(r0 + 3) * CD + col0 + lane];

  f32x32 s0, s1, s2, s3;
#pragma unroll
  for (int t = 0; t < 32; t++) { s0[t] = NEGS; s1[t] = NEGS; s2[t] = NEGS; s3[t] = NEGS; }

  // ---- Phase 1: scores ----
  for (int jt = 0; jt < ntiles; jt++) {
    const int j0 = jt * 64;
#pragma unroll
    for (int i = 0; i < 4; i++) {  // stage 64x64 fp32 K tile, b128
      const int fidx = i * 256 + tid;
      const int jr = fidx >> 4, c4 = (fidx & 15) * 4;
      *reinterpret_cast<float4*>(&KT[jr][c4]) =
          *reinterpret_cast<const float4*>(&k[(size_t)(j0 + jr) * CD + col0 + c4]);
    }
    __syncthreads();
    float a0 = 0.f, a1 = 0.f, a2 = 0.f, a3 = 0.f;
#pragma unroll
    for (int c = 0; c < 16; c++) {
      const float4 kv = *reinterpret_cast<const float4*>(&KT[lane][c * 4]);
      const float ke[4] = {kv.x, kv.y, kv.z, kv.w};
#pragma unroll
      for (int e = 0; e < 4; e++) {  // k ascending: same order as rounds 2-4
        a0 = fmaf(rl_f(qr0, c * 4 + e), ke[e], a0);
        a1 = fmaf(rl_f(qr1, c * 4 + e), ke[e], a1);
        a2 = fmaf(rl_f(qr2, c * 4 + e), ke[e], a2);
        a3 = fmaf(rl_f(qr3, c * 4 + e), ke[e], a3);
      }
    }
    const int col = j0 + lane;
    s0[jt] = (col <= r0 + 0) ? a0 * 0.125f : NEGS;
    s1[jt] = (col <= r0 + 1) ? a1 * 0.125f : NEGS;
    s2[jt] = (col <= r0 + 2) ? a2 * 0.125f : NEGS;
    s3[jt] = (col <= r0 + 3) ? a3 * 0.125f : NEGS;
    __syncthreads();
  }

  // ---- Phase 2: entmax (registers + wave shuffles only) ----
  const float inv0 = entmax_row(s0, r0 + 1);
  const float inv1 = entmax_row(s1, r0 + 2);
  const float inv2 = entmax_row(s2, r0 + 3);
  const float inv3 = entmax_row(s3, r0 + 4);

  // ---- Phase 3: p @ V ----
  float acc0 = 0.f, acc1 = 0.f, acc2 = 0.f, acc3 = 0.f;
  for (int jt = 0; jt < ntiles; jt++) {
    const int j0 = jt * 64;
#pragma unroll
    for (int i = 0; i < 4; i++) {  // stage 64x64 fp32 V tile
      const int fidx = i * 256 + tid;
      const int jr = fidx >> 4, c4 = (fidx & 15) * 4;
      *reinterpret_cast<float4*>(&KT[jr][c4]) =
          *reinterpret_cast<const float4*>(&v[(size_t)(j0 + jr) * CD + col0 + c4]);
    }
    __syncthreads();
    const float pv0 = s0[jt], pv1 = s1[jt], pv2 = s2[jt], pv3 = s3[jt];
    int lim = r0 + 3 - j0 + 1;  // wave-uniform; p==0 pads shorter rows
    lim = lim < 0 ? 0 : (lim > 64 ? 64 : lim);
    for (int j = 0; j < lim; j++) {
      const float vv = KT[j][lane];  // row read: 2-way -> free
      acc0 = fmaf(rl_f(pv0, j), vv, acc0);
      acc1 = fmaf(rl_f(pv1, j), vv, acc1);
      acc2 = fmaf(rl_f(pv2, j), vv, acc2);
      acc3 = fmaf(rl_f(pv3, j), vv, acc3);
    }
    __syncthreads();
  }

  // ---- Epilogue: split o into bf16 hi/lo planes for the Wo MFMA GEMM ----
  const float oo[4] = {acc0 * inv0, acc1 * inv1, acc2 * inv2, acc3 * inv3};
#pragma unroll
  for (int i = 0; i < 4; i++) {
    __hip_bfloat16 bh = __float2bfloat16(oo[i]);
    __hip_bfloat16 bl = __float2bfloat16(oo[i] - __bfloat162float(bh));
    oh[(size_t)(r0 + i) * CD + col0 + lane] = __builtin_bit_cast(short, bh);
    ol[(size_t)(r0 + i) * CD + col0 + lane] = __builtin_bit_cast(short, bl);
  }
}

extern "C" void kernel_launch(void* const* d_in, const int* in_sizes, int n_in,
                              void* d_out, int out_size, void* d_ws, size_t ws_size,
                              hipStream_t stream) {
  const float* x  = (const float*)d_in[0];
  const float* Wq = (const float*)d_in[1];
  const float* Wk = (const float*)d_in[2];
  const float* Wv = (const float*)d_in[3];
  const float* Wo = (const float*)d_in[4];
  float* out = (float*)d_out;

  // Workspace layout (56 MB total)
  char* ws = (char*)d_ws;
  float* qf  = (float*)(ws + (0ull  << 20));  // 8 MB fp32 q
  float* kf  = (float*)(ws + (8ull  << 20));  // 8 MB fp32 k
  float* vf  = (float*)(ws + (16ull << 20));  // 8 MB fp32 v
  short* xh  = (short*)(ws + (24ull << 20));  // 4 MB
  short* xl  = (short*)(ws + (28ull << 20));  // 4 MB
  short* wqh = (short*)(ws + (32ull << 20));  // 2 MB each below
  short* wql = (short*)(ws + (34ull << 20));
  short* wkh = (short*)(ws + (36ull << 20));
  short* wkl = (short*)(ws + (38ull << 20));
  short* wvh = (short*)(ws + (40ull << 20));
  short* wvl = (short*)(ws + (42ull << 20));
  short* woh = (short*)(ws + (44ull << 20));
  short* wol = (short*)(ws + (46ull << 20));
  short* oh  = (short*)(ws + (48ull << 20));  // 4 MB
  short* ol  = (short*)(ws + (52ull << 20));  // 4 MB

  // Split fp32 inputs into bf16 hi/lo planes
  split_bf16<<<2048, 256, 0, stream>>>(x,  xh,  xl,  (CL * CD) / 4);
  split_bf16<<<1024, 256, 0, stream>>>(Wq, wqh, wql, (CD * CD) / 4);
  split_bf16<<<1024, 256, 0, stream>>>(Wk, wkh, wkl, (CD * CD) / 4);
  split_bf16<<<1024, 256, 0, stream>>>(Wv, wvh, wvl, (CD * CD) / 4);
  split_bf16<<<1024, 256, 0, stream>>>(Wo, woh, wol, (CD * CD) / 4);

  // Fused QKV: grid.x = 24 -> sel = x>>3 picks (Wq,qf)/(Wk,kf)/(Wv,vf)
  gemm128_split<<<dim3(24, CL / 128), 256, 0, stream>>>(
      xh, xl, wqh, wql, wkh, wkl, wvh, wvl, qf, kf, vf);

  attn_entmax5<<<dim3(CL / 16, CH), 256, 0, stream>>>(qf, kf, vf, oh, ol);

  // Wo: grid.x = 8 -> sel = 0
  gemm128_split<<<dim3(8, CL / 128), 256, 0, stream>>>(
      oh, ol, woh, wol, woh, wol, woh, wol, out, out, out);
}

// Round 6
// 518.537 us; speedup vs baseline: 1.6910x; 1.6910x over previous
//
#include <hip/hip_runtime.h>
#include <hip/hip_bf16.h>

// Problem constants (B=1)
#define CL 2048   // sequence length
#define CD 1024   // hidden
#define CH 16     // heads
#define CHD 64    // head dim
#define NEGS -1e30f

typedef __attribute__((ext_vector_type(8))) short short8;  // 8 x bf16 frag
typedef __attribute__((ext_vector_type(4))) float f32x4;
// First-class SSA vector for row scores -> never alloca'd (round-4 spill fix).
typedef __attribute__((ext_vector_type(32))) float f32x32;

__device__ __forceinline__ float wave_sum(float x) {
#pragma unroll
  for (int m = 32; m >= 1; m >>= 1) x += __shfl_xor(x, m, 64);
  return x;  // all 64 lanes hold the total
}

__device__ __forceinline__ void split1(float v, short& h, short& l) {
  __hip_bfloat16 bh = __float2bfloat16(v);
  __hip_bfloat16 bl = __float2bfloat16(v - __bfloat162float(bh));
  h = __builtin_bit_cast(short, bh);
  l = __builtin_bit_cast(short, bl);
}

// fp32 -> (hi, lo) bf16 planes: x ~= hi + lo to ~16 mantissa bits.
__global__ __launch_bounds__(256) void split_bf16(
    const float* __restrict__ x, short* __restrict__ hi, short* __restrict__ lo,
    int n4) {
  const int i = blockIdx.x * 256 + threadIdx.x;
  if (i >= n4) return;
  const float4 v = reinterpret_cast<const float4*>(x)[i];
  const float vv[4] = {v.x, v.y, v.z, v.w};
  short hh[4], ll[4];
#pragma unroll
  for (int e = 0; e < 4; e++) split1(vv[e], hh[e], ll[e]);
  reinterpret_cast<short4*>(hi)[i] = make_short4(hh[0], hh[1], hh[2], hh[3]);
  reinterpret_cast<short4*>(lo)[i] = make_short4(ll[0], ll[1], ll[2], ll[3]);
}

// C[2048,1024] = (Ah+Al) * (B?h+B?l)^T via 3-term split-bf16 MFMA.
// 128x128 tile/WG, LDS-staged BK=32, 4 waves (2x2), wave tile 64x64.
// Epilogue: fp32out -> Cf (Wo GEMM); else split C into bf16 hi/lo planes:
//   sel 0 -> q planes row-major, sel 1 -> k planes row-major,
//   sel 2 -> vT planes TRANSPOSED [dim][seq] (B-operand layout for P@V MFMA).
__global__ __launch_bounds__(256, 2) void gemm128_split(
    const short* __restrict__ Ah, const short* __restrict__ Al,
    const short* __restrict__ B0h, const short* __restrict__ B0l,
    const short* __restrict__ B1h, const short* __restrict__ B1l,
    const short* __restrict__ B2h, const short* __restrict__ B2l,
    short* __restrict__ O0h, short* __restrict__ O0l,
    short* __restrict__ O1h, short* __restrict__ O1l,
    short* __restrict__ O2h, short* __restrict__ O2l,
    float* __restrict__ Cf, int fp32out) {
  __shared__ short AhS[128][32], AlS[128][32], BhS[128][32], BlS[128][32];
  const int tid = threadIdx.x, lane = tid & 63, wave = tid >> 6;
  const int l15 = lane & 15, quad = lane >> 4;
  const int sel = blockIdx.x >> 3, nb = blockIdx.x & 7;
  const short* Bh = sel == 0 ? B0h : (sel == 1 ? B1h : B2h);
  const short* Bl = sel == 0 ? B0l : (sel == 1 ? B1l : B2l);
  const int m0 = blockIdx.y * 128, n0 = nb * 128;
  const int wm = (wave >> 1) * 64, wn = (wave & 1) * 64;

  f32x4 acc[4][4];
#pragma unroll
  for (int i = 0; i < 4; i++)
#pragma unroll
    for (int j = 0; j < 4; j++) acc[i][j] = {0.f, 0.f, 0.f, 0.f};

  // Staging: wave p owns plane p (Ah/Al/Bh/Bl), 8 KB each per k-step.
  const short* gsrc = wave == 0 ? Ah : wave == 1 ? Al : wave == 2 ? Bh : Bl;
  short(*ldst)[32] = wave == 0 ? AhS : wave == 1 ? AlS : wave == 2 ? BhS : BlS;
  const int srow0 = (wave < 2) ? m0 : n0;

  for (int k0 = 0; k0 < CD; k0 += 32) {
#pragma unroll
    for (int i = 0; i < 8; i++) {
      const int ci = i * 64 + lane;        // 0..511 16B-chunks
      const int r = ci >> 2, kc = (ci & 3) * 8;
      *reinterpret_cast<short8*>(&ldst[r][kc]) =
          *reinterpret_cast<const short8*>(&gsrc[(size_t)(srow0 + r) * CD + k0 + kc]);
    }
    __syncthreads();
    short8 a_h[4], a_l[4], b_h[4], b_l[4];
#pragma unroll
    for (int i = 0; i < 4; i++) {
      a_h[i] = *reinterpret_cast<const short8*>(&AhS[wm + i * 16 + l15][quad * 8]);
      a_l[i] = *reinterpret_cast<const short8*>(&AlS[wm + i * 16 + l15][quad * 8]);
      b_h[i] = *reinterpret_cast<const short8*>(&BhS[wn + i * 16 + l15][quad * 8]);
      b_l[i] = *reinterpret_cast<const short8*>(&BlS[wn + i * 16 + l15][quad * 8]);
    }
#pragma unroll
    for (int im = 0; im < 4; im++)
#pragma unroll
      for (int in = 0; in < 4; in++) {  // same 3-term order as rounds 3-5
        acc[im][in] = __builtin_amdgcn_mfma_f32_16x16x32_bf16(a_h[im], b_l[in], acc[im][in], 0, 0, 0);
        acc[im][in] = __builtin_amdgcn_mfma_f32_16x16x32_bf16(a_l[im], b_h[in], acc[im][in], 0, 0, 0);
        acc[im][in] = __builtin_amdgcn_mfma_f32_16x16x32_bf16(a_h[im], b_h[in], acc[im][in], 0, 0, 0);
      }
    __syncthreads();
  }

#pragma unroll
  for (int im = 0; im < 4; im++)
#pragma unroll
    for (int in = 0; in < 4; in++)
#pragma unroll
      for (int r = 0; r < 4; r++) {
        const int mr = m0 + wm + im * 16 + quad * 4 + r;
        const int nc = n0 + wn + in * 16 + l15;
        const float val = acc[im][in][r];
        if (fp32out) {
          Cf[(size_t)mr * CD + nc] = val;
        } else {
          short sh, sl;
          split1(val, sh, sl);
          if (sel == 0) {
            O0h[(size_t)mr * CD + nc] = sh; O0l[(size_t)mr * CD + nc] = sl;
          } else if (sel == 1) {
            O1h[(size_t)mr * CD + nc] = sh; O1l[(size_t)mr * CD + nc] = sl;
          } else {  // transposed: vT[dim][seq]; WG covers 128 consecutive rows
            O2h[(size_t)nc * CL + mr] = sh; O2l[(size_t)nc * CL + mr] = sl;
          }
        }
      }
}

// Per-row entmax on register scores s[0..31] (col = 64t + lane), NEGS = invalid.
// Bit-identical arithmetic order to the round-2..5 passing versions.
__device__ __forceinline__ float entmax_row(f32x32& s, int n) {
  float ssum = 0.f;
#pragma unroll
  for (int t = 0; t < 32; t++) {
    const float sv = s[t];
    if (sv > -1e29f) ssum += sv;
  }
  ssum = wave_sum(ssum);

  float tau = (ssum - 1.f) / (float)n;
  int cnt = n;
  for (int it = 0; it < 1024; it++) {
    float cs = 0.f, cn = 0.f;
#pragma unroll
    for (int t = 0; t < 32; t++) {
      const float sv = s[t];
      if (sv > tau) { cs += sv; cn += 1.f; }  // NEGS never > tau
    }
    cs = wave_sum(cs);
    cn = wave_sum(cn);
    const int newcnt = (int)cn;
    tau = (cs - 1.f) / cn;
    if (newcnt == cnt) break;
    cnt = newcnt;
  }

  // Reference quirk: tau_star uses the FULL masked row sum, not the top-k sum.
  const float tau_star = (ssum - 1.f) / (float)cnt;
  float psum = 0.f;
#pragma unroll
  for (int t = 0; t < 32; t++) {
    float p = s[t] - tau_star;
    p = p > 0.f ? p : 0.f;
    s[t] = p;
    psum += p;
  }
  psum = wave_sum(psum);
  return 1.f / (psum + 1e-10f);
}

// WG = 256 thr (4 waves) x (head h, 16 query rows).
// Phase 1: scores = Q·K^T via 4-term split MFMA (16 rows x 64 cols per tile,
//   wave w computes col-block w), LDS round-trip into f32x32 row registers.
// Phase 2: register Michelot (unchanged).
// Phase 3: P@V via 3-term split MFMA; P split to bf16 planes per tile in LDS;
//   V read from pre-transposed vT planes in B-frag layout straight from global.
__global__ __launch_bounds__(256, 1) void attn_mfma(
    const short* __restrict__ qh, const short* __restrict__ ql,
    const short* __restrict__ kh, const short* __restrict__ kl,
    const short* __restrict__ vhT, const short* __restrict__ vlT,
    short* __restrict__ oh, short* __restrict__ ol) {
  __shared__ float Stile[16][68];  // 4.35 KB score/P tile; pad 68 for b128 align
  __shared__ float invS[16];

  const int tid = threadIdx.x, lane = tid & 63, wave = tid >> 6;
  const int l15 = lane & 15, quad = lane >> 4;
  // heavy+light pairing: bx even -> low q-blocks, odd -> mirrored high blocks
  const int bx = blockIdx.x;
  const int qb = (bx & 1) ? (127 - (bx >> 1)) : (bx >> 1);
  const int h = blockIdx.y, q0 = qb * 16;
  const int col0 = h * CHD;
  const int r0 = q0 + wave * 4;               // this wave's 4 rows
  const int ntiles = (q0 + 79) >> 6;          // cols 0..q0+15

  // A-frags (Q, 16 rows x 64 k): m=l15, k=kb*32+quad*8+j  [m89/m91 layout]
  short8 a_h[2], a_l[2];
  {
    const size_t qbase = (size_t)(q0 + l15) * CD + col0 + quad * 8;
#pragma unroll
    for (int kb = 0; kb < 2; kb++) {
      a_h[kb] = *reinterpret_cast<const short8*>(qh + qbase + kb * 32);
      a_l[kb] = *reinterpret_cast<const short8*>(ql + qbase + kb * 32);
    }
  }

  f32x32 s0, s1, s2, s3;
#pragma unroll
  for (int t = 0; t < 32; t++) { s0[t] = NEGS; s1[t] = NEGS; s2[t] = NEGS; s3[t] = NEGS; }

  // ---- Phase 1: scores ----
  for (int jt = 0; jt < ntiles; jt++) {
    const int j0 = jt * 64;
    // B-frags: K rows j0 + wave*16 + l15 (this wave's 16 seq-cols)
    const size_t kbase = (size_t)(j0 + wave * 16 + l15) * CD + col0 + quad * 8;
    f32x4 c = {0.f, 0.f, 0.f, 0.f};
#pragma unroll
    for (int kb = 0; kb < 2; kb++) {
      const short8 b_h = *reinterpret_cast<const short8*>(kh + kbase + kb * 32);
      const short8 b_l = *reinterpret_cast<const short8*>(kl + kbase + kb * 32);
      // 4-term: exact (qh+ql)(kh+kl) product, fp32 accumulation
      c = __builtin_amdgcn_mfma_f32_16x16x32_bf16(a_l[kb], b_l, c, 0, 0, 0);
      c = __builtin_amdgcn_mfma_f32_16x16x32_bf16(a_h[kb], b_l, c, 0, 0, 0);
      c = __builtin_amdgcn_mfma_f32_16x16x32_bf16(a_l[kb], b_h, c, 0, 0, 0);
      c = __builtin_amdgcn_mfma_f32_16x16x32_bf16(a_h[kb], b_h, c, 0, 0, 0);
    }
    // C layout: col(seq) = wave*16+l15, row(q) = quad*4+r
#pragma unroll
    for (int r = 0; r < 4; r++) Stile[quad * 4 + r][wave * 16 + l15] = c[r];
    __syncthreads();
    const int col = j0 + lane;
    {
      const float v0 = Stile[wave * 4 + 0][lane] * 0.125f;
      const float v1 = Stile[wave * 4 + 1][lane] * 0.125f;
      const float v2 = Stile[wave * 4 + 2][lane] * 0.125f;
      const float v3 = Stile[wave * 4 + 3][lane] * 0.125f;
      s0[jt] = (col <= r0 + 0) ? v0 : NEGS;
      s1[jt] = (col <= r0 + 1) ? v1 : NEGS;
      s2[jt] = (col <= r0 + 2) ? v2 : NEGS;
      s3[jt] = (col <= r0 + 3) ? v3 : NEGS;
    }
    __syncthreads();
  }

  // ---- Phase 2: entmax (registers + wave shuffles only) ----
  const float inv0 = entmax_row(s0, r0 + 1);
  const float inv1 = entmax_row(s1, r0 + 2);
  const float inv2 = entmax_row(s2, r0 + 3);
  const float inv3 = entmax_row(s3, r0 + 4);
  if (lane == 0) {
    invS[wave * 4 + 0] = inv0; invS[wave * 4 + 1] = inv1;
    invS[wave * 4 + 2] = inv2; invS[wave * 4 + 3] = inv3;
  }

  // ---- Phase 3: P @ V via MFMA (wave w owns head-dim block w) ----
  f32x4 acc = {0.f, 0.f, 0.f, 0.f};
  for (int jt = 0; jt < ntiles; jt++) {
    const int j0 = jt * 64;
    // write this wave's 4 rows of P (unnormalized; zeros where masked)
    Stile[wave * 4 + 0][lane] = s0[jt];
    Stile[wave * 4 + 1][lane] = s1[jt];
    Stile[wave * 4 + 2][lane] = s2[jt];
    Stile[wave * 4 + 3][lane] = s3[jt];
    __syncthreads();
#pragma unroll
    for (int kb = 0; kb < 2; kb++) {
      // A-frag: P[m=l15][k=kb*32+quad*8+j] -> split to bf16 hi/lo
      const float4 p0 = *reinterpret_cast<const float4*>(&Stile[l15][kb * 32 + quad * 8]);
      const float4 p1 = *reinterpret_cast<const float4*>(&Stile[l15][kb * 32 + quad * 8 + 4]);
      const float pe[8] = {p0.x, p0.y, p0.z, p0.w, p1.x, p1.y, p1.z, p1.w};
      short8 pah, pal;
#pragma unroll
      for (int j = 0; j < 8; j++) {
        short sh, sl;
        split1(pe[j], sh, sl);
        pah[j] = sh; pal[j] = sl;
      }
      // B-frag: vT[n=col0+wave*16+l15][k=j0+kb*32+quad*8+j]
      const size_t vbase =
          (size_t)(col0 + wave * 16 + l15) * CL + j0 + kb * 32 + quad * 8;
      const short8 vb_h = *reinterpret_cast<const short8*>(vhT + vbase);
      const short8 vb_l = *reinterpret_cast<const short8*>(vlT + vbase);
      acc = __builtin_amdgcn_mfma_f32_16x16x32_bf16(pah, vb_l, acc, 0, 0, 0);
      acc = __builtin_amdgcn_mfma_f32_16x16x32_bf16(pal, vb_h, acc, 0, 0, 0);
      acc = __builtin_amdgcn_mfma_f32_16x16x32_bf16(pah, vb_h, acc, 0, 0, 0);
    }
    __syncthreads();
  }

  // ---- Epilogue: normalize per row, split to bf16 hi/lo for the Wo GEMM ----
#pragma unroll
  for (int r = 0; r < 4; r++) {
    const float o = acc[r] * invS[quad * 4 + r];
    short sh, sl;
    split1(o, sh, sl);
    const size_t oidx = (size_t)(q0 + quad * 4 + r) * CD + col0 + wave * 16 + l15;
    oh[oidx] = sh;
    ol[oidx] = sl;
  }
}

extern "C" void kernel_launch(void* const* d_in, const int* in_sizes, int n_in,
                              void* d_out, int out_size, void* d_ws, size_t ws_size,
                              hipStream_t stream) {
  const float* x  = (const float*)d_in[0];
  const float* Wq = (const float*)d_in[1];
  const float* Wk = (const float*)d_in[2];
  const float* Wv = (const float*)d_in[3];
  const float* Wo = (const float*)d_in[4];
  float* out = (float*)d_out;

  // Workspace layout (56 MB total)
  char* ws = (char*)d_ws;
  short* xh  = (short*)(ws + (0ull  << 20));  // 4 MB
  short* xl  = (short*)(ws + (4ull  << 20));  // 4 MB
  short* wqh = (short*)(ws + (8ull  << 20));  // 2 MB each below
  short* wql = (short*)(ws + (10ull << 20));
  short* wkh = (short*)(ws + (12ull << 20));
  short* wkl = (short*)(ws + (14ull << 20));
  short* wvh = (short*)(ws + (16ull << 20));
  short* wvl = (short*)(ws + (18ull << 20));
  short* woh = (short*)(ws + (20ull << 20));
  short* wol = (short*)(ws + (22ull << 20));
  short* qhp = (short*)(ws + (24ull << 20));  // 4 MB each below
  short* qlp = (short*)(ws + (28ull << 20));
  short* khp = (short*)(ws + (32ull << 20));
  short* klp = (short*)(ws + (36ull << 20));
  short* vhT = (short*)(ws + (40ull << 20));
  short* vlT = (short*)(ws + (44ull << 20));
  short* ohp = (short*)(ws + (48ull << 20));
  short* olp = (short*)(ws + (52ull << 20));

  // Split fp32 inputs into bf16 hi/lo planes
  split_bf16<<<2048, 256, 0, stream>>>(x,  xh,  xl,  (CL * CD) / 4);
  split_bf16<<<1024, 256, 0, stream>>>(Wq, wqh, wql, (CD * CD) / 4);
  split_bf16<<<1024, 256, 0, stream>>>(Wk, wkh, wkl, (CD * CD) / 4);
  split_bf16<<<1024, 256, 0, stream>>>(Wv, wvh, wvl, (CD * CD) / 4);
  split_bf16<<<1024, 256, 0, stream>>>(Wo, woh, wol, (CD * CD) / 4);

  // Fused QKV: grid.x = 24, sel = x>>3 -> q/k planes row-major, vT transposed
  gemm128_split<<<dim3(24, CL / 128), 256, 0, stream>>>(
      xh, xl, wqh, wql, wkh, wkl, wvh, wvl,
      qhp, qlp, khp, klp, vhT, vlT, nullptr, 0);

  attn_mfma<<<dim3(CL / 16, CH), 256, 0, stream>>>(
      qhp, qlp, khp, klp, vhT, vlT, ohp, olp);

  // Wo: grid.x = 8 (sel = 0), fp32 out
  gemm128_split<<<dim3(8, CL / 128), 256, 0, stream>>>(
      ohp, olp, woh, wol, woh, wol, woh, wol,
      ohp, olp, ohp, olp, ohp, olp, out, 1);
}